// Round 12
// baseline (506.618 us; speedup 1.0000x reference)
//
#include <hip/hip_runtime.h>

// TaxoRec forward pipeline on MI355X — round 12.
// Node feature rows padded to 128 f32 (512 B): cols 0..62 enc1, 63..125 enc2.
// mega1 = passA (radix partition) || prep (node+tag maps).
// mega2 = passB2 (per-bucket offsets+scatter) || hyper (staged 128x64 GEMM,
// KSPLIT=4). stage now lives in dedicated ws after rec (not b2), so pb
// (42 MB) fits b1+b2-head, disjoint from stage/rec/off -> full K-split grid
// (1376 blocks = 5.4/CU) without aliasing hazards.
// Gather: 16-edge unrolled loop (floored at ~3.6 TB/s random service rate).

#define KSPLIT 4
#define NBUK 96          // N / 512
#define CAP 18432        // bucket capacity; mean 16384, sigma 127 -> safe

__device__ __forceinline__ float wsum(float v) {
#pragma unroll
  for (int m = 32; m; m >>= 1) v += __shfl_xor(v, m, 64);
  return v;
}

__device__ __forceinline__ float logmap_scale(float ss) {
  float x0 = sqrtf(1.0f + ss);
  float alpha = fmaxf(x0, 1.0f + 1e-7f);
  float rnorm = sqrtf(fmaxf(ss, 1e-15f));
  return acoshf(alpha) / rnorm;
}

// ---- mega1: passA || prep ----------------------------------------------

__device__ void passA_body(
    const int* __restrict__ esrc, const int* __restrict__ edst,
    const float* __restrict__ ew, int* __restrict__ bcur,
    int2* __restrict__ stage, int bx) {
  __shared__ int lh[128];
  __shared__ int lscan[128];
  __shared__ int lcur[128];
  __shared__ int gb[128];
  __shared__ unsigned int keyb[2048];
  __shared__ float wvb[2048];
  int tid = threadIdx.x;
  int base = bx * 2048;
  if (tid < 128) lh[tid] = 0;
  __syncthreads();
  unsigned int key[8]; float wv[8];
#pragma unroll
  for (int r = 0; r < 8; ++r) {
    int e = base + r * 256 + tid;
    int d = edst[e];
    key[r] = ((unsigned int)d << 16) | (unsigned int)esrc[e];
    wv[r] = ew[e];
    atomicAdd(&lh[d >> 9], 1);
  }
  __syncthreads();
  if (tid < 128) lscan[tid] = lh[tid];
  __syncthreads();
  for (int d = 1; d < 128; d <<= 1) {
    int v = (tid < 128 && tid >= d) ? lscan[tid - d] : 0;
    __syncthreads();
    if (tid < 128) lscan[tid] += v;
    __syncthreads();
  }
  if (tid < 128) {
    int excl = lscan[tid] - lh[tid];
    lscan[tid] = excl;
    lcur[tid] = 0;
    if (tid < NBUK && lh[tid] > 0) {
      int rsv = atomicAdd(&bcur[tid], lh[tid]);
      gb[tid] = tid * CAP + rsv;
    }
  }
  __syncthreads();
#pragma unroll
  for (int r = 0; r < 8; ++r) {
    int b = key[r] >> 25;
    int lp = lscan[b] + atomicAdd(&lcur[b], 1);
    keyb[lp] = key[r];
    wvb[lp] = wv[r];
  }
  __syncthreads();
#pragma unroll
  for (int r = 0; r < 8; ++r) {
    int i = r * 256 + tid;
    unsigned int k2 = keyb[i];
    int b = k2 >> 25;
    stage[gb[b] + (i - lscan[b])] = make_int2((int)k2, __float_as_int(wvb[i]));
  }
}

__device__ void prep_body(
    const float* __restrict__ emb, const float* __restrict__ ugr,
    const float* __restrict__ Tw, float* __restrict__ xt,
    float* __restrict__ gkg, int N, int NU, int TAGS, int pbx) {
  int n = pbx * 4 + (threadIdx.x >> 6);
  int lane = threadIdx.x & 63;
  if (n < N) {
    size_t base = (size_t)n * 128;
    float r1 = (lane < 63) ? emb[(size_t)n * 64 + 1 + lane] : 0.0f;
    float sc1 = logmap_scale(wsum(r1 * r1));
    if (lane < 63) xt[base + lane] = sc1 * r1;
    if (lane == 63) { xt[base + 126] = 0.0f; xt[base + 127] = 0.0f; }
    if (n < NU) {
      float r2 = (lane < 63) ? ugr[(size_t)n * 64 + 1 + lane] : 0.0f;
      float sc2 = logmap_scale(wsum(r2 * r2));
      if (lane < 63) xt[base + 63 + lane] = sc2 * r2;
    }
  } else if (n < N + TAGS) {
    int t = n - N;
    float r = (lane < 63) ? Tw[(size_t)t * 64 + 1 + lane] : 0.0f;
    float ss = wsum(r * r);
    float x0 = sqrtf(1.0f + ss);
    float p = r / (x0 + 1.0f);          // l2p (sk = 1)
    float sp = wsum(p * p);
    float k = 2.0f * p / (1.0f + sp);   // p2k
    float sk2 = wsum(k * k);
    float gamma = 1.0f / sqrtf(fmaxf(1.0f - sk2, 1e-15f));
    gkg[(size_t)t * 64 + lane] = (lane < 63) ? gamma * k : gamma;
  }
}

__global__ __launch_bounds__(256) void k_mega1(
    const int* __restrict__ esrc, const int* __restrict__ edst,
    const float* __restrict__ ew, int* __restrict__ bcur,
    int2* __restrict__ stage,
    const float* __restrict__ emb, const float* __restrict__ ugr,
    const float* __restrict__ Tw, float* __restrict__ xt,
    float* __restrict__ gkg, int N, int NU, int TAGS, int nA) {
  if ((int)blockIdx.x < nA)
    passA_body(esrc, edst, ew, bcur, stage, blockIdx.x);
  else
    prep_body(emb, ugr, Tw, xt, gkg, N, NU, TAGS, blockIdx.x - nA);
}

// ---- mega2: passB2 || hyper (staged, verified load pattern) --------------

__device__ void passB2_body(
    const int2* __restrict__ stage, const int* __restrict__ bcur,
    int* __restrict__ off, int2* __restrict__ rec, int N, int E) {
  __shared__ int hist[512];
  __shared__ int pairs[256];
  __shared__ int cur[512];
  __shared__ int bs[128];
  int b = blockIdx.x, tid = threadIdx.x;
  if (tid < 128) bs[tid] = (tid < NBUK) ? min(bcur[tid], CAP) : 0;
  hist[tid] = 0; hist[tid + 256] = 0;
  __syncthreads();
  for (int d = 1; d < 128; d <<= 1) {
    int v = (tid < 128 && tid >= d) ? bs[tid - d] : 0;
    __syncthreads();
    if (tid < 128) bs[tid] += v;
    __syncthreads();
  }
  int cnt = min(bcur[b], CAP);
  int base = bs[b] - cnt;                 // exclusive bucket base
  if (b == 0 && tid == 0) off[N] = E;
  const int2* sg = stage + (size_t)b * CAP;
  for (int i = tid; i < cnt; i += 256)
    atomicAdd(&hist[((unsigned int)sg[i].x >> 16) & 511], 1);
  __syncthreads();
  int h0 = hist[2 * tid], h1 = hist[2 * tid + 1];
  int ps = h0 + h1;
  pairs[tid] = ps;
  __syncthreads();
  for (int d = 1; d < 256; d <<= 1) {
    int v = (tid >= d) ? pairs[tid - d] : 0;
    __syncthreads();
    pairs[tid] += v;
    __syncthreads();
  }
  int e0 = base + pairs[tid] - ps;        // exclusive prefix for dst 2*tid
  int e1 = e0 + h0;
  int gd = b * 512 + 2 * tid;
  off[gd] = e0;      cur[2 * tid] = e0;
  off[gd + 1] = e1;  cur[2 * tid + 1] = e1;
  __syncthreads();
  for (int i = tid; i < cnt; i += 256) {
    int2 r = sg[i];
    unsigned int k2 = (unsigned int)r.x;
    int d = (int)((k2 >> 16) & 511);
    int p = atomicAdd(&cur[d], 1);
    rec[p] = make_int2((int)(k2 & 0xFFFF), r.y);
  }
}

// hyper GEMM: 128 items x 64 dims per block, K = 1024/KSPLIT tags.
// Staged coalesced sps + gkg tiles; conflict-free LDS reads (stride 36).
// Accumulation order per item identical to verified rounds 4-10.
__device__ void hyper_body(
    const float* __restrict__ sps, const float* __restrict__ gkg,
    float* __restrict__ pb, int NI, int bx, int ksp) {
  __shared__ float s_tile[128][36];
  __shared__ float g_tile[32][64];
  int tid = threadIdx.x;
  int tx = tid & 15, ty = tid >> 4;
  int sx = tid & 7,  sy = tid >> 3;   // s staging: 8 f4-cols x 32 rows
  int gx = tid & 15, gy = tid >> 4;   // g staging: 16 f4-cols x 16 rows
  int ib = bx * 128;
  int kbase = ksp * (1024 / KSPLIT);
  float acc[8][4];
#pragma unroll
  for (int c = 0; c < 8; ++c)
#pragma unroll
    for (int d = 0; d < 4; ++d) acc[c][d] = 0.0f;

  const float4* sps4 = (const float4*)sps;
  const float4* gkg4 = (const float4*)gkg;

  for (int kc = 0; kc < (1024 / KSPLIT) / 32; ++kc) {   // chunks of 32 tags
    int t4b = (kbase >> 2) + kc * 8;
#pragma unroll
    for (int r = 0; r < 4; ++r) {
      int row = sy + 32 * r;
      *(float4*)&s_tile[row][sx * 4] = sps4[(size_t)(ib + row) * 256 + t4b + sx];
    }
#pragma unroll
    for (int r = 0; r < 2; ++r) {
      int grow = gy + 16 * r;
      *(float4*)&g_tile[grow][gx * 4] =
          gkg4[(size_t)(kbase + kc * 32 + grow) * 16 + gx];
    }
    __syncthreads();
#pragma unroll
    for (int tg = 0; tg < 8; ++tg) {
      float4 g4[4];
#pragma unroll
      for (int j = 0; j < 4; ++j)
        g4[j] = *(const float4*)&g_tile[tg * 4 + j][tx * 4];
#pragma unroll
      for (int c = 0; c < 8; ++c) {
        float4 s4 = *(const float4*)&s_tile[ty + 16 * c][tg * 4];
        float sv[4] = {s4.x, s4.y, s4.z, s4.w};
#pragma unroll
        for (int j = 0; j < 4; ++j) {
          acc[c][0] = fmaf(sv[j], g4[j].x, acc[c][0]);
          acc[c][1] = fmaf(sv[j], g4[j].y, acc[c][1]);
          acc[c][2] = fmaf(sv[j], g4[j].z, acc[c][2]);
          acc[c][3] = fmaf(sv[j], g4[j].w, acc[c][3]);
        }
      }
    }
    __syncthreads();
  }

  float* dst = pb + ((size_t)ksp * NI + ib) * 64;
#pragma unroll
  for (int c = 0; c < 8; ++c)
    *(float4*)&dst[(size_t)(ty + 16 * c) * 64 + tx * 4] =
        make_float4(acc[c][0], acc[c][1], acc[c][2], acc[c][3]);
}

__global__ __launch_bounds__(256) void k_mega2(
    const int2* __restrict__ stage, const int* __restrict__ bcur,
    int* __restrict__ off, int2* __restrict__ rec,
    const float* __restrict__ sps, const float* __restrict__ gkg,
    float* __restrict__ pb, int NI, int N, int E) {
  if ((int)blockIdx.x < NBUK) {
    passB2_body(stage, bcur, off, rec, N, E);
  } else {
    int hb = blockIdx.x - NBUK;
    int nbx = NI / 128;
    hyper_body(sps, gkg, pb, NI, hb % nbx, hb / nbx);
  }
}

// sum the KSPLIT partials, then k2p -> p2l -> logmap0; wave per item.
__global__ __launch_bounds__(256) void k_combine(
    const float* __restrict__ pb, float* __restrict__ xt, int NI, int NU) {
  int i = blockIdx.x * 4 + (threadIdx.x >> 6);
  if (i >= NI) return;
  int lane = threadIdx.x & 63;
  float v = 0.0f;
#pragma unroll
  for (int s = 0; s < KSPLIT; ++s) v += pb[((size_t)s * NI + i) * 64 + lane];
  float den = fmaxf(__shfl(v, 63, 64), 1e-15f);
  float y = v / den;
  float sy = wsum((lane < 63) ? y * y : 0.0f);
  float dk = 1.0f + sqrtf(fmaxf(1.0f - sy, 1e-15f));
  float q = y / dk;
  float nq = wsum((lane < 63) ? q * q : 0.0f);
  float f = 1.0f / (1.0f - nq + 1e-6f);
  float row0 = (1.0f + nq) * f;
  float r = 2.0f * q * f;
  float srr = wsum((lane < 63) ? r * r : 0.0f);
  float alpha = fmaxf(row0, 1.0f + 1e-7f);
  float scale = acoshf(alpha) / sqrtf(fmaxf(srr, 1e-15f));
  if (lane < 63)
    xt[(size_t)(NU + i) * 128 + 63 + lane] = scale * r;
}

// ---- gather core: 16 edges/iter, 8 row-loads in flight per half-wave ----
__device__ __forceinline__ float4 gather_row(
    const float* __restrict__ cur, const int* __restrict__ off,
    const int2* __restrict__ rec, int n, int lane) {
  int half = lane >> 5;
  int q = lane & 31;
  const float4* cq = (const float4*)cur + q;
  int beg = off[n], end = off[n + 1];
  float4 acc = make_float4(0.0f, 0.0f, 0.0f, 0.0f);
  for (int j = beg; j < end; j += 64) {
    int cnt = min(64, end - j);
    int sv = 0; float wv = 0.0f;
    if (lane < cnt) {
      int2 rc = rec[j + lane];
      sv = rc.x;
      wv = __int_as_float(rc.y);
    }
    int k = 0;
    for (; k + 16 <= cnt; k += 16) {
      int s[8]; float w[8]; float4 v[8];
#pragma unroll
      for (int u = 0; u < 8; ++u) {
        int e = k + 2 * u + half;
        s[u] = __shfl(sv, e, 64);
        w[u] = __shfl(wv, e, 64);
      }
#pragma unroll
      for (int u = 0; u < 8; ++u) v[u] = cq[(size_t)s[u] * 32];
#pragma unroll
      for (int u = 0; u < 8; ++u) {
        acc.x = fmaf(w[u], v[u].x, acc.x);
        acc.y = fmaf(w[u], v[u].y, acc.y);
        acc.z = fmaf(w[u], v[u].z, acc.z);
        acc.w = fmaf(w[u], v[u].w, acc.w);
      }
    }
    for (; k + 8 <= cnt; k += 8) {
      int s[4]; float w[4]; float4 v[4];
#pragma unroll
      for (int u = 0; u < 4; ++u) {
        int e = k + 2 * u + half;
        s[u] = __shfl(sv, e, 64);
        w[u] = __shfl(wv, e, 64);
      }
#pragma unroll
      for (int u = 0; u < 4; ++u) v[u] = cq[(size_t)s[u] * 32];
#pragma unroll
      for (int u = 0; u < 4; ++u) {
        acc.x = fmaf(w[u], v[u].x, acc.x);
        acc.y = fmaf(w[u], v[u].y, acc.y);
        acc.z = fmaf(w[u], v[u].z, acc.z);
        acc.w = fmaf(w[u], v[u].w, acc.w);
      }
    }
    for (; k + 2 <= cnt; k += 2) {
      int e = k + half;
      int s0 = __shfl(sv, e, 64);
      float w0 = __shfl(wv, e, 64);
      float4 v = cq[(size_t)s0 * 32];
      acc.x = fmaf(w0, v.x, acc.x);
      acc.y = fmaf(w0, v.y, acc.y);
      acc.z = fmaf(w0, v.z, acc.z);
      acc.w = fmaf(w0, v.w, acc.w);
    }
    if (k < cnt) {
      int s0 = __shfl(sv, k, 64);
      float w0 = __shfl(wv, k, 64);
      if (half == 0) {
        float4 v = cq[(size_t)s0 * 32];
        acc.x = fmaf(w0, v.x, acc.x);
        acc.y = fmaf(w0, v.y, acc.y);
        acc.z = fmaf(w0, v.z, acc.z);
        acc.w = fmaf(w0, v.w, acc.w);
      }
    }
  }
  acc.x += __shfl_xor(acc.x, 32, 64);
  acc.y += __shfl_xor(acc.y, 32, 64);
  acc.z += __shfl_xor(acc.z, 32, 64);
  acc.w += __shfl_xor(acc.w, 32, 64);
  return acc;
}

// layers 1,2: plain gather, write full row once.
__global__ __launch_bounds__(256) void k_gather(
    const float* __restrict__ cur, float* __restrict__ nxt,
    const int* __restrict__ off, const int2* __restrict__ rec, int N) {
  int n = blockIdx.x * 4 + (threadIdx.x >> 6);
  if (n >= N) return;
  int lane = threadIdx.x & 63;
  float4 acc = gather_row(cur, off, rec, n, lane);
  if (lane < 32) ((float4*)(nxt + (size_t)n * 128))[lane] = acc;
}

// layer 3 fused with expmap: h[n] = [expmap0(enc1) | expmap0(enc2)].
// Shifted store via lane shuffles (no LDS, no barrier). h aliases b1.
__global__ __launch_bounds__(256) void k_gather_exp(
    const float* __restrict__ cur, const float* b1, const float* __restrict__ b2,
    const int* __restrict__ off, const int2* __restrict__ rec,
    float* h, int N) {
  int n = blockIdx.x * 4 + (threadIdx.x >> 6);
  if (n >= N) return;
  int lane = threadIdx.x & 63;
  int q = lane & 31;
  float4 a3 = gather_row(cur, off, rec, n, lane);
  size_t b = (size_t)n * 128;
  float4 r1 = ((const float4*)(b1 + b))[q];
  float4 r2 = ((const float4*)(b2 + b))[q];
  float vv[4] = {a3.x + r1.x + r2.x, a3.y + r1.y + r2.y,
                 a3.z + r1.z + r2.z, a3.w + r1.w + r2.w};
  float p0 = 0.0f, p1 = 0.0f;
#pragma unroll
  for (int i = 0; i < 4; ++i) {
    int c = 4 * q + i;
    if (c < 63) p0 += vv[i] * vv[i]; else p1 += vv[i] * vv[i];
  }
  float ss0 = 0.5f * wsum(p0);         // halves hold duplicate copies
  float ss1 = 0.5f * wsum(p1);
  float nn0 = sqrtf(fmaxf(ss0, 1e-15f)), nn1 = sqrtf(fmaxf(ss1, 1e-15f));
  float s0 = sinhf(nn0) / nn0, s1 = sinhf(nn1) / nn1;
  int prev = (lane == 0) ? 0 : lane - 1;
  float pv2 = __shfl(vv[2], prev, 64);
  float pv3 = __shfl(vv[3], prev, 64);
  if (lane < 32) {
    float4 o;
    if (q < 16) {
      o.x = (q == 0) ? coshf(nn0) : s0 * pv3;
      o.y = s0 * vv[0]; o.z = s0 * vv[1]; o.w = s0 * vv[2];
    } else {
      o.x = (q == 16) ? coshf(nn1) : s1 * pv2;
      o.y = s1 * pv3; o.z = s1 * vv[0]; o.w = s1 * vv[1];
    }
    ((float4*)(h + b))[q] = o;
  }
}

// out[b] = min(dist2(.,.),50) + min(dist2(.,.),15); 4 pairs per wave.
__global__ __launch_bounds__(256) void k_score(
    const float* __restrict__ h, const int* __restrict__ idx,
    float* __restrict__ out, int B) {
  int w = blockIdx.x * 4 + (threadIdx.x >> 6);
  int lane = threadIdx.x & 63;
  int b0 = w * 4;
  if (b0 >= B) return;
  int np = min(4, B - b0);
  float2 hu[4], hv[4];
#pragma unroll
  for (int p = 0; p < 4; ++p) {
    int bb = b0 + ((p < np) ? p : 0);
    int u = idx[2 * bb], v = idx[2 * bb + 1];
    hu[p] = ((const float2*)(h + (size_t)u * 128))[lane];
    hv[p] = ((const float2*)(h + (size_t)v * 128))[lane];
  }
#pragma unroll
  for (int p = 0; p < 4; ++p) {
    if (p >= np) break;
    float px = hu[p].x * hv[p].x;
    if (lane == 0 || lane == 32) px = -px;   // time comps at cols 0 and 64
    float pp = px + hu[p].y * hv[p].y;
#pragma unroll
    for (int m = 1; m < 32; m <<= 1) pp += __shfl_xor(pp, m, 64);
    float dd = fmaxf(-pp, 1.0f + 1e-7f);
    float a = acoshf(dd);
    float s = fminf(a * a, (lane < 32) ? 50.0f : 15.0f);
    s += __shfl_xor(s, 32, 64);
    if (lane == 0) out[b0 + p] = s;
  }
}

extern "C" void kernel_launch(void* const* d_in, const int* in_sizes, int n_in,
                              void* d_out, int out_size, void* d_ws, size_t ws_size,
                              hipStream_t stream) {
  const float* emb = (const float*)d_in[0];
  const float* Tw  = (const float*)d_in[1];
  const float* ugr = (const float*)d_in[2];
  const float* sps = (const float*)d_in[3];
  const float* ew  = (const float*)d_in[4];
  const int* esrc  = (const int*)d_in[5];
  const int* edst  = (const int*)d_in[6];
  const int* idx   = (const int*)d_in[7];
  float* out = (float*)d_out;

  const int N    = in_sizes[0] / 64;   // 49152
  const int TAGS = in_sizes[1] / 64;   // 1024
  const int NU   = in_sizes[2] / 64;   // 8192
  const int NI   = in_sizes[3] / TAGS; // 40960
  const int E    = in_sizes[4];        // 1572864
  const int B    = in_sizes[7] / 2;    // 131072

  size_t rowsz = (size_t)N * 128 * sizeof(float);
  char* ws = (char*)d_ws;
  float* xt  = (float*)(ws);               // encoder layer-0 input
  float* b1  = (float*)(ws + rowsz);       // layer1 out; pb head; h alias
  float* b2  = (float*)(ws + 2 * rowsz);   // layer2 out; pb tail
  float* gkg = (float*)(ws + 3 * rowsz);   // TAGS x 64
  size_t o = 3 * rowsz + (size_t)TAGS * 64 * sizeof(float);
  int* off   = (int*)(ws + o);  o += (size_t)(N + 1) * sizeof(int);
  int* bcur  = (int*)(ws + o);  o += (size_t)NBUK * sizeof(int);
  o = (o + 7) & ~(size_t)7;
  int2* rec = (int2*)(ws + o);  o += (size_t)E * sizeof(int2);
  int2* stage = (int2*)(ws + o);           // NBUK x CAP records (14.2 MB),
                                           // dedicated ws (total ~102.9 MB,
                                           // under round-1-proven >=113.9 MB)
  float* pb = b1;                          // KSPLIT=4 x NI x 64 partials
                                           // (42 MB = b1 + b2 head; disjoint
                                           // from stage/rec/off during mega2)
  float* h  = b1;                          // final embeddings, in-place over b1

  const int nA = E / 2048;                 // 768 passA blocks
  const int nPrep = (N + TAGS + 3) / 4;    // prep blocks
  const int nHyper = (NI / 128) * KSPLIT;  // 1280 hyper blocks

  hipMemsetAsync(bcur, 0, (size_t)NBUK * sizeof(int), stream);
  // mega1: passA || prep (independent outputs)
  k_mega1<<<nA + nPrep, 256, 0, stream>>>(esrc, edst, ew, bcur, stage,
                                          emb, ugr, Tw, xt, gkg, N, NU, TAGS, nA);
  // mega2: passB2 (stage->rec/off) || hyper (sps,gkg->pb); disjoint buffers
  k_mega2<<<NBUK + nHyper, 256, 0, stream>>>(stage, bcur, off, rec,
                                             sps, gkg, pb, NI, N, E);
  k_combine<<<(NI + 3) / 4, 256, 0, stream>>>(pb, xt, NI, NU);

  // 3 encoder layers (gather-side); layer 3 fused with expmap
  k_gather<<<(N + 3) / 4, 256, 0, stream>>>(xt, b1, off, rec, N);
  k_gather<<<(N + 3) / 4, 256, 0, stream>>>(b1, b2, off, rec, N);
  k_gather_exp<<<(N + 3) / 4, 256, 0, stream>>>(b2, b1, b2, off, rec, h, N);

  k_score<<<(B / 4 + 3) / 4, 256, 0, stream>>>(h, idx, out, B);
}

// Round 13
// 506.294 us; speedup vs baseline: 1.0006x; 1.0006x over previous
//
#include <hip/hip_runtime.h>

// TaxoRec forward pipeline on MI355X — round 13.
// Node feature rows padded to 128 f32 (512 B): cols 0..62 enc1, 63..125 enc2.
// mega1 = passA (radix partition) || prep (node+tag maps).
// mega2 = passB2 || hyper with an EXPLICIT LDS UNION (26624 B, was 32256 as
// the sum of both bodies) -> 6 blocks/CU instead of 4; KSPLIT=4 grid (1376
// blocks) now fully co-resident. Bodies unchanged from verified versions.
// Gather: 16-edge unrolled loop (floored at ~3.6 TB/s random service rate).

#define KSPLIT 4
#define NBUK 96          // N / 512
#define CAP 18432        // bucket capacity; mean 16384, sigma 127 -> safe
#define MEGA2_SMEM 26624 // max(hyper 26624, passB2 5632)

__device__ __forceinline__ float wsum(float v) {
#pragma unroll
  for (int m = 32; m; m >>= 1) v += __shfl_xor(v, m, 64);
  return v;
}

__device__ __forceinline__ float logmap_scale(float ss) {
  float x0 = sqrtf(1.0f + ss);
  float alpha = fmaxf(x0, 1.0f + 1e-7f);
  float rnorm = sqrtf(fmaxf(ss, 1e-15f));
  return acoshf(alpha) / rnorm;
}

// ---- mega1: passA || prep ----------------------------------------------

__device__ void passA_body(
    const int* __restrict__ esrc, const int* __restrict__ edst,
    const float* __restrict__ ew, int* __restrict__ bcur,
    int2* __restrict__ stage, int bx) {
  __shared__ int lh[128];
  __shared__ int lscan[128];
  __shared__ int lcur[128];
  __shared__ int gb[128];
  __shared__ unsigned int keyb[2048];
  __shared__ float wvb[2048];
  int tid = threadIdx.x;
  int base = bx * 2048;
  if (tid < 128) lh[tid] = 0;
  __syncthreads();
  unsigned int key[8]; float wv[8];
#pragma unroll
  for (int r = 0; r < 8; ++r) {
    int e = base + r * 256 + tid;
    int d = edst[e];
    key[r] = ((unsigned int)d << 16) | (unsigned int)esrc[e];
    wv[r] = ew[e];
    atomicAdd(&lh[d >> 9], 1);
  }
  __syncthreads();
  if (tid < 128) lscan[tid] = lh[tid];
  __syncthreads();
  for (int d = 1; d < 128; d <<= 1) {
    int v = (tid < 128 && tid >= d) ? lscan[tid - d] : 0;
    __syncthreads();
    if (tid < 128) lscan[tid] += v;
    __syncthreads();
  }
  if (tid < 128) {
    int excl = lscan[tid] - lh[tid];
    lscan[tid] = excl;
    lcur[tid] = 0;
    if (tid < NBUK && lh[tid] > 0) {
      int rsv = atomicAdd(&bcur[tid], lh[tid]);
      gb[tid] = tid * CAP + rsv;
    }
  }
  __syncthreads();
#pragma unroll
  for (int r = 0; r < 8; ++r) {
    int b = key[r] >> 25;
    int lp = lscan[b] + atomicAdd(&lcur[b], 1);
    keyb[lp] = key[r];
    wvb[lp] = wv[r];
  }
  __syncthreads();
#pragma unroll
  for (int r = 0; r < 8; ++r) {
    int i = r * 256 + tid;
    unsigned int k2 = keyb[i];
    int b = k2 >> 25;
    stage[gb[b] + (i - lscan[b])] = make_int2((int)k2, __float_as_int(wvb[i]));
  }
}

__device__ void prep_body(
    const float* __restrict__ emb, const float* __restrict__ ugr,
    const float* __restrict__ Tw, float* __restrict__ xt,
    float* __restrict__ gkg, int N, int NU, int TAGS, int pbx) {
  int n = pbx * 4 + (threadIdx.x >> 6);
  int lane = threadIdx.x & 63;
  if (n < N) {
    size_t base = (size_t)n * 128;
    float r1 = (lane < 63) ? emb[(size_t)n * 64 + 1 + lane] : 0.0f;
    float sc1 = logmap_scale(wsum(r1 * r1));
    if (lane < 63) xt[base + lane] = sc1 * r1;
    if (lane == 63) { xt[base + 126] = 0.0f; xt[base + 127] = 0.0f; }
    if (n < NU) {
      float r2 = (lane < 63) ? ugr[(size_t)n * 64 + 1 + lane] : 0.0f;
      float sc2 = logmap_scale(wsum(r2 * r2));
      if (lane < 63) xt[base + 63 + lane] = sc2 * r2;
    }
  } else if (n < N + TAGS) {
    int t = n - N;
    float r = (lane < 63) ? Tw[(size_t)t * 64 + 1 + lane] : 0.0f;
    float ss = wsum(r * r);
    float x0 = sqrtf(1.0f + ss);
    float p = r / (x0 + 1.0f);          // l2p (sk = 1)
    float sp = wsum(p * p);
    float k = 2.0f * p / (1.0f + sp);   // p2k
    float sk2 = wsum(k * k);
    float gamma = 1.0f / sqrtf(fmaxf(1.0f - sk2, 1e-15f));
    gkg[(size_t)t * 64 + lane] = (lane < 63) ? gamma * k : gamma;
  }
}

__global__ __launch_bounds__(256) void k_mega1(
    const int* __restrict__ esrc, const int* __restrict__ edst,
    const float* __restrict__ ew, int* __restrict__ bcur,
    int2* __restrict__ stage,
    const float* __restrict__ emb, const float* __restrict__ ugr,
    const float* __restrict__ Tw, float* __restrict__ xt,
    float* __restrict__ gkg, int N, int NU, int TAGS, int nA) {
  if ((int)blockIdx.x < nA)
    passA_body(esrc, edst, ew, bcur, stage, blockIdx.x);
  else
    prep_body(emb, ugr, Tw, xt, gkg, N, NU, TAGS, blockIdx.x - nA);
}

// ---- mega2: passB2 || hyper, shared LDS union ----------------------------

__device__ void passB2_body(
    const int2* __restrict__ stage, const int* __restrict__ bcur,
    int* __restrict__ off, int2* __restrict__ rec, int N, int E,
    char* smem) {
  int* hist  = (int*)smem;                 // 512 ints
  int* cur   = (int*)(smem + 2048);        // 512 ints
  int* pairs = (int*)(smem + 4096);        // 256 ints
  int* bs    = (int*)(smem + 5120);        // 128 ints
  int b = blockIdx.x, tid = threadIdx.x;
  if (tid < 128) bs[tid] = (tid < NBUK) ? min(bcur[tid], CAP) : 0;
  hist[tid] = 0; hist[tid + 256] = 0;
  __syncthreads();
  for (int d = 1; d < 128; d <<= 1) {
    int v = (tid < 128 && tid >= d) ? bs[tid - d] : 0;
    __syncthreads();
    if (tid < 128) bs[tid] += v;
    __syncthreads();
  }
  int cnt = min(bcur[b], CAP);
  int base = bs[b] - cnt;                 // exclusive bucket base
  if (b == 0 && tid == 0) off[N] = E;
  const int2* sg = stage + (size_t)b * CAP;
  for (int i = tid; i < cnt; i += 256)
    atomicAdd(&hist[((unsigned int)sg[i].x >> 16) & 511], 1);
  __syncthreads();
  int h0 = hist[2 * tid], h1 = hist[2 * tid + 1];
  int ps = h0 + h1;
  pairs[tid] = ps;
  __syncthreads();
  for (int d = 1; d < 256; d <<= 1) {
    int v = (tid >= d) ? pairs[tid - d] : 0;
    __syncthreads();
    pairs[tid] += v;
    __syncthreads();
  }
  int e0 = base + pairs[tid] - ps;        // exclusive prefix for dst 2*tid
  int e1 = e0 + h0;
  int gd = b * 512 + 2 * tid;
  off[gd] = e0;      cur[2 * tid] = e0;
  off[gd + 1] = e1;  cur[2 * tid + 1] = e1;
  __syncthreads();
  for (int i = tid; i < cnt; i += 256) {
    int2 r = sg[i];
    unsigned int k2 = (unsigned int)r.x;
    int d = (int)((k2 >> 16) & 511);
    int p = atomicAdd(&cur[d], 1);
    rec[p] = make_int2((int)(k2 & 0xFFFF), r.y);
  }
}

// hyper GEMM: 128 items x 64 dims per block, K = 1024/KSPLIT tags.
// Staged coalesced sps + gkg tiles; conflict-free LDS reads (stride 36).
// Accumulation order per item identical to verified rounds 4-12.
__device__ void hyper_body(
    const float* __restrict__ sps, const float* __restrict__ gkg,
    float* __restrict__ pb, int NI, int bx, int ksp, char* smem) {
  float (*s_tile)[36] = (float(*)[36])smem;            // 128x36 = 18432 B
  float (*g_tile)[64] = (float(*)[64])(smem + 18432);  // 32x64  =  8192 B
  int tid = threadIdx.x;
  int tx = tid & 15, ty = tid >> 4;
  int sx = tid & 7,  sy = tid >> 3;   // s staging: 8 f4-cols x 32 rows
  int gx = tid & 15, gy = tid >> 4;   // g staging: 16 f4-cols x 16 rows
  int ib = bx * 128;
  int kbase = ksp * (1024 / KSPLIT);
  float acc[8][4];
#pragma unroll
  for (int c = 0; c < 8; ++c)
#pragma unroll
    for (int d = 0; d < 4; ++d) acc[c][d] = 0.0f;

  const float4* sps4 = (const float4*)sps;
  const float4* gkg4 = (const float4*)gkg;

  for (int kc = 0; kc < (1024 / KSPLIT) / 32; ++kc) {   // chunks of 32 tags
    int t4b = (kbase >> 2) + kc * 8;
#pragma unroll
    for (int r = 0; r < 4; ++r) {
      int row = sy + 32 * r;
      *(float4*)&s_tile[row][sx * 4] = sps4[(size_t)(ib + row) * 256 + t4b + sx];
    }
#pragma unroll
    for (int r = 0; r < 2; ++r) {
      int grow = gy + 16 * r;
      *(float4*)&g_tile[grow][gx * 4] =
          gkg4[(size_t)(kbase + kc * 32 + grow) * 16 + gx];
    }
    __syncthreads();
#pragma unroll
    for (int tg = 0; tg < 8; ++tg) {
      float4 g4[4];
#pragma unroll
      for (int j = 0; j < 4; ++j)
        g4[j] = *(const float4*)&g_tile[tg * 4 + j][tx * 4];
#pragma unroll
      for (int c = 0; c < 8; ++c) {
        float4 s4 = *(const float4*)&s_tile[ty + 16 * c][tg * 4];
        float sv[4] = {s4.x, s4.y, s4.z, s4.w};
#pragma unroll
        for (int j = 0; j < 4; ++j) {
          acc[c][0] = fmaf(sv[j], g4[j].x, acc[c][0]);
          acc[c][1] = fmaf(sv[j], g4[j].y, acc[c][1]);
          acc[c][2] = fmaf(sv[j], g4[j].z, acc[c][2]);
          acc[c][3] = fmaf(sv[j], g4[j].w, acc[c][3]);
        }
      }
    }
    __syncthreads();
  }

  float* dst = pb + ((size_t)ksp * NI + ib) * 64;
#pragma unroll
  for (int c = 0; c < 8; ++c)
    *(float4*)&dst[(size_t)(ty + 16 * c) * 64 + tx * 4] =
        make_float4(acc[c][0], acc[c][1], acc[c][2], acc[c][3]);
}

__global__ __launch_bounds__(256) void k_mega2(
    const int2* __restrict__ stage, const int* __restrict__ bcur,
    int* __restrict__ off, int2* __restrict__ rec,
    const float* __restrict__ sps, const float* __restrict__ gkg,
    float* __restrict__ pb, int NI, int N, int E) {
  __shared__ __align__(16) char smem[MEGA2_SMEM];
  if ((int)blockIdx.x < NBUK) {
    passB2_body(stage, bcur, off, rec, N, E, smem);
  } else {
    int hb = blockIdx.x - NBUK;
    int nbx = NI / 128;
    hyper_body(sps, gkg, pb, NI, hb % nbx, hb / nbx, smem);
  }
}

// sum the KSPLIT partials, then k2p -> p2l -> logmap0; wave per item.
__global__ __launch_bounds__(256) void k_combine(
    const float* __restrict__ pb, float* __restrict__ xt, int NI, int NU) {
  int i = blockIdx.x * 4 + (threadIdx.x >> 6);
  if (i >= NI) return;
  int lane = threadIdx.x & 63;
  float v = 0.0f;
#pragma unroll
  for (int s = 0; s < KSPLIT; ++s) v += pb[((size_t)s * NI + i) * 64 + lane];
  float den = fmaxf(__shfl(v, 63, 64), 1e-15f);
  float y = v / den;
  float sy = wsum((lane < 63) ? y * y : 0.0f);
  float dk = 1.0f + sqrtf(fmaxf(1.0f - sy, 1e-15f));
  float q = y / dk;
  float nq = wsum((lane < 63) ? q * q : 0.0f);
  float f = 1.0f / (1.0f - nq + 1e-6f);
  float row0 = (1.0f + nq) * f;
  float r = 2.0f * q * f;
  float srr = wsum((lane < 63) ? r * r : 0.0f);
  float alpha = fmaxf(row0, 1.0f + 1e-7f);
  float scale = acoshf(alpha) / sqrtf(fmaxf(srr, 1e-15f));
  if (lane < 63)
    xt[(size_t)(NU + i) * 128 + 63 + lane] = scale * r;
}

// ---- gather core: 16 edges/iter, 8 row-loads in flight per half-wave ----
__device__ __forceinline__ float4 gather_row(
    const float* __restrict__ cur, const int* __restrict__ off,
    const int2* __restrict__ rec, int n, int lane) {
  int half = lane >> 5;
  int q = lane & 31;
  const float4* cq = (const float4*)cur + q;
  int beg = off[n], end = off[n + 1];
  float4 acc = make_float4(0.0f, 0.0f, 0.0f, 0.0f);
  for (int j = beg; j < end; j += 64) {
    int cnt = min(64, end - j);
    int sv = 0; float wv = 0.0f;
    if (lane < cnt) {
      int2 rc = rec[j + lane];
      sv = rc.x;
      wv = __int_as_float(rc.y);
    }
    int k = 0;
    for (; k + 16 <= cnt; k += 16) {
      int s[8]; float w[8]; float4 v[8];
#pragma unroll
      for (int u = 0; u < 8; ++u) {
        int e = k + 2 * u + half;
        s[u] = __shfl(sv, e, 64);
        w[u] = __shfl(wv, e, 64);
      }
#pragma unroll
      for (int u = 0; u < 8; ++u) v[u] = cq[(size_t)s[u] * 32];
#pragma unroll
      for (int u = 0; u < 8; ++u) {
        acc.x = fmaf(w[u], v[u].x, acc.x);
        acc.y = fmaf(w[u], v[u].y, acc.y);
        acc.z = fmaf(w[u], v[u].z, acc.z);
        acc.w = fmaf(w[u], v[u].w, acc.w);
      }
    }
    for (; k + 8 <= cnt; k += 8) {
      int s[4]; float w[4]; float4 v[4];
#pragma unroll
      for (int u = 0; u < 4; ++u) {
        int e = k + 2 * u + half;
        s[u] = __shfl(sv, e, 64);
        w[u] = __shfl(wv, e, 64);
      }
#pragma unroll
      for (int u = 0; u < 4; ++u) v[u] = cq[(size_t)s[u] * 32];
#pragma unroll
      for (int u = 0; u < 4; ++u) {
        acc.x = fmaf(w[u], v[u].x, acc.x);
        acc.y = fmaf(w[u], v[u].y, acc.y);
        acc.z = fmaf(w[u], v[u].z, acc.z);
        acc.w = fmaf(w[u], v[u].w, acc.w);
      }
    }
    for (; k + 2 <= cnt; k += 2) {
      int e = k + half;
      int s0 = __shfl(sv, e, 64);
      float w0 = __shfl(wv, e, 64);
      float4 v = cq[(size_t)s0 * 32];
      acc.x = fmaf(w0, v.x, acc.x);
      acc.y = fmaf(w0, v.y, acc.y);
      acc.z = fmaf(w0, v.z, acc.z);
      acc.w = fmaf(w0, v.w, acc.w);
    }
    if (k < cnt) {
      int s0 = __shfl(sv, k, 64);
      float w0 = __shfl(wv, k, 64);
      if (half == 0) {
        float4 v = cq[(size_t)s0 * 32];
        acc.x = fmaf(w0, v.x, acc.x);
        acc.y = fmaf(w0, v.y, acc.y);
        acc.z = fmaf(w0, v.z, acc.z);
        acc.w = fmaf(w0, v.w, acc.w);
      }
    }
  }
  acc.x += __shfl_xor(acc.x, 32, 64);
  acc.y += __shfl_xor(acc.y, 32, 64);
  acc.z += __shfl_xor(acc.z, 32, 64);
  acc.w += __shfl_xor(acc.w, 32, 64);
  return acc;
}

// layers 1,2: plain gather, write full row once.
__global__ __launch_bounds__(256) void k_gather(
    const float* __restrict__ cur, float* __restrict__ nxt,
    const int* __restrict__ off, const int2* __restrict__ rec, int N) {
  int n = blockIdx.x * 4 + (threadIdx.x >> 6);
  if (n >= N) return;
  int lane = threadIdx.x & 63;
  float4 acc = gather_row(cur, off, rec, n, lane);
  if (lane < 32) ((float4*)(nxt + (size_t)n * 128))[lane] = acc;
}

// layer 3 fused with expmap: h[n] = [expmap0(enc1) | expmap0(enc2)].
// Shifted store via lane shuffles (no LDS, no barrier). h aliases b1.
__global__ __launch_bounds__(256) void k_gather_exp(
    const float* __restrict__ cur, const float* b1, const float* __restrict__ b2,
    const int* __restrict__ off, const int2* __restrict__ rec,
    float* h, int N) {
  int n = blockIdx.x * 4 + (threadIdx.x >> 6);
  if (n >= N) return;
  int lane = threadIdx.x & 63;
  int q = lane & 31;
  float4 a3 = gather_row(cur, off, rec, n, lane);
  size_t b = (size_t)n * 128;
  float4 r1 = ((const float4*)(b1 + b))[q];
  float4 r2 = ((const float4*)(b2 + b))[q];
  float vv[4] = {a3.x + r1.x + r2.x, a3.y + r1.y + r2.y,
                 a3.z + r1.z + r2.z, a3.w + r1.w + r2.w};
  float p0 = 0.0f, p1 = 0.0f;
#pragma unroll
  for (int i = 0; i < 4; ++i) {
    int c = 4 * q + i;
    if (c < 63) p0 += vv[i] * vv[i]; else p1 += vv[i] * vv[i];
  }
  float ss0 = 0.5f * wsum(p0);         // halves hold duplicate copies
  float ss1 = 0.5f * wsum(p1);
  float nn0 = sqrtf(fmaxf(ss0, 1e-15f)), nn1 = sqrtf(fmaxf(ss1, 1e-15f));
  float s0 = sinhf(nn0) / nn0, s1 = sinhf(nn1) / nn1;
  int prev = (lane == 0) ? 0 : lane - 1;
  float pv2 = __shfl(vv[2], prev, 64);
  float pv3 = __shfl(vv[3], prev, 64);
  if (lane < 32) {
    float4 o;
    if (q < 16) {
      o.x = (q == 0) ? coshf(nn0) : s0 * pv3;
      o.y = s0 * vv[0]; o.z = s0 * vv[1]; o.w = s0 * vv[2];
    } else {
      o.x = (q == 16) ? coshf(nn1) : s1 * pv2;
      o.y = s1 * pv3; o.z = s1 * vv[0]; o.w = s1 * vv[1];
    }
    ((float4*)(h + b))[q] = o;
  }
}

// out[b] = min(dist2(.,.),50) + min(dist2(.,.),15); 4 pairs per wave.
__global__ __launch_bounds__(256) void k_score(
    const float* __restrict__ h, const int* __restrict__ idx,
    float* __restrict__ out, int B) {
  int w = blockIdx.x * 4 + (threadIdx.x >> 6);
  int lane = threadIdx.x & 63;
  int b0 = w * 4;
  if (b0 >= B) return;
  int np = min(4, B - b0);
  float2 hu[4], hv[4];
#pragma unroll
  for (int p = 0; p < 4; ++p) {
    int bb = b0 + ((p < np) ? p : 0);
    int u = idx[2 * bb], v = idx[2 * bb + 1];
    hu[p] = ((const float2*)(h + (size_t)u * 128))[lane];
    hv[p] = ((const float2*)(h + (size_t)v * 128))[lane];
  }
#pragma unroll
  for (int p = 0; p < 4; ++p) {
    if (p >= np) break;
    float px = hu[p].x * hv[p].x;
    if (lane == 0 || lane == 32) px = -px;   // time comps at cols 0 and 64
    float pp = px + hu[p].y * hv[p].y;
#pragma unroll
    for (int m = 1; m < 32; m <<= 1) pp += __shfl_xor(pp, m, 64);
    float dd = fmaxf(-pp, 1.0f + 1e-7f);
    float a = acoshf(dd);
    float s = fminf(a * a, (lane < 32) ? 50.0f : 15.0f);
    s += __shfl_xor(s, 32, 64);
    if (lane == 0) out[b0 + p] = s;
  }
}

extern "C" void kernel_launch(void* const* d_in, const int* in_sizes, int n_in,
                              void* d_out, int out_size, void* d_ws, size_t ws_size,
                              hipStream_t stream) {
  const float* emb = (const float*)d_in[0];
  const float* Tw  = (const float*)d_in[1];
  const float* ugr = (const float*)d_in[2];
  const float* sps = (const float*)d_in[3];
  const float* ew  = (const float*)d_in[4];
  const int* esrc  = (const int*)d_in[5];
  const int* edst  = (const int*)d_in[6];
  const int* idx   = (const int*)d_in[7];
  float* out = (float*)d_out;

  const int N    = in_sizes[0] / 64;   // 49152
  const int TAGS = in_sizes[1] / 64;   // 1024
  const int NU   = in_sizes[2] / 64;   // 8192
  const int NI   = in_sizes[3] / TAGS; // 40960
  const int E    = in_sizes[4];        // 1572864
  const int B    = in_sizes[7] / 2;    // 131072

  size_t rowsz = (size_t)N * 128 * sizeof(float);
  char* ws = (char*)d_ws;
  float* xt  = (float*)(ws);               // encoder layer-0 input
  float* b1  = (float*)(ws + rowsz);       // layer1 out; pb head; h alias
  float* b2  = (float*)(ws + 2 * rowsz);   // layer2 out; pb tail
  float* gkg = (float*)(ws + 3 * rowsz);   // TAGS x 64
  size_t o = 3 * rowsz + (size_t)TAGS * 64 * sizeof(float);
  int* off   = (int*)(ws + o);  o += (size_t)(N + 1) * sizeof(int);
  int* bcur  = (int*)(ws + o);  o += (size_t)NBUK * sizeof(int);
  o = (o + 7) & ~(size_t)7;
  int2* rec = (int2*)(ws + o);  o += (size_t)E * sizeof(int2);
  int2* stage = (int2*)(ws + o);           // NBUK x CAP records (14.2 MB),
                                           // dedicated ws (~102.9 MB total)
  float* pb = b1;                          // KSPLIT=4 x NI x 64 partials
                                           // (42 MB = b1 + b2 head; disjoint
                                           // from stage/rec/off during mega2)
  float* h  = b1;                          // final embeddings, in-place over b1

  const int nA = E / 2048;                 // 768 passA blocks
  const int nPrep = (N + TAGS + 3) / 4;    // prep blocks
  const int nHyper = (NI / 128) * KSPLIT;  // 1280 hyper blocks

  hipMemsetAsync(bcur, 0, (size_t)NBUK * sizeof(int), stream);
  // mega1: passA || prep (independent outputs)
  k_mega1<<<nA + nPrep, 256, 0, stream>>>(esrc, edst, ew, bcur, stage,
                                          emb, ugr, Tw, xt, gkg, N, NU, TAGS, nA);
  // mega2: passB2 (stage->rec/off) || hyper (sps,gkg->pb); LDS union 26624 B
  k_mega2<<<NBUK + nHyper, 256, 0, stream>>>(stage, bcur, off, rec,
                                             sps, gkg, pb, NI, N, E);
  k_combine<<<(NI + 3) / 4, 256, 0, stream>>>(pb, xt, NI, NU);

  // 3 encoder layers (gather-side); layer 3 fused with expmap
  k_gather<<<(N + 3) / 4, 256, 0, stream>>>(xt, b1, off, rec, N);
  k_gather<<<(N + 3) / 4, 256, 0, stream>>>(b1, b2, off, rec, N);
  k_gather_exp<<<(N + 3) / 4, 256, 0, stream>>>(b2, b1, b2, off, rec, h, N);

  k_score<<<(B / 4 + 3) / 4, 256, 0, stream>>>(h, idx, out, B);
}